// Round 12
// baseline (197.177 us; speedup 1.0000x reference)
//
#include <hip/hip_runtime.h>
#include <hip/hip_bf16.h>
#include <math.h>

#define NSENT 65536
#define NBAGS 4096
#define DIM 768
#define D4 192            // float4 per row
#define FLATC 53
#define CPAD 64           // padded class count for probs MFMA
#define KTOT 2304         // 3*DIM
#define K4 576            // KTOT/4
#define GB 8              // bags per block
#define NW 8              // waves per block (512 threads)
#define CHF 256           // sentences per online chunk

typedef short bf16x8 __attribute__((ext_vector_type(8)));
typedef float f32x4 __attribute__((ext_vector_type(4)));

__device__ __forceinline__ float wsum(float v) {
#pragma unroll
  for (int o = 32; o; o >>= 1) v += __shfl_xor(v, o);
  return v;
}
__device__ __forceinline__ float wmax(float v) {
#pragma unroll
  for (int o = 32; o; o >>= 1) v = fmaxf(v, __shfl_xor(v, o));
  return v;
}
__device__ __forceinline__ float dot4(float4 a, float4 b) {
  return a.x * b.x + a.y * b.y + a.z * b.z + a.w * b.w;
}
__device__ __forceinline__ unsigned short f2bf(float f) {
  union { __hip_bfloat16 b; unsigned short s; } cv;
  cv.b = __float2bfloat16(f);
  return cv.s;
}
__device__ __forceinline__ ushort4 pk4(float4 v) {
  ushort4 h;
  h.x = f2bf(v.x); h.y = f2bf(v.y); h.z = f2bf(v.z); h.w = f2bf(v.w);
  return h;
}

// ---- K1: relation_weight f32[53][2304] -> bf16 padded [64][2304] ----
__global__ __launch_bounds__(256) void rwcvt(const float* __restrict__ rw,
                                             unsigned short* __restrict__ rw16) {
  const int idx = blockIdx.x * 256 + threadIdx.x;
  if (idx < CPAD * KTOT) {
    const int row = idx / KTOT;
    rw16[idx] = f2bf(row < FLATC ? rw[idx] : 0.f);
  }
}

// ---- K2: FUSED logits + online softmax + aggregation ----
// 512 blocks x 512 threads. Block owns 8 consecutive bags (contiguous
// sentence span). Online chunks of 256 sentences:
//   pass1: all 8 waves compute chunk logits (R4 dual-sentence gather-dot)
//   pass2: wave w owns bag w: chunk-max -> rescale -> weighted accumulate
//          (x rows L1/L2-hot from pass1; stats wave-uniform, no reductions)
__global__ __launch_bounds__(512) void fused8(
    const float* __restrict__ x, const int* __restrict__ q,
    const float* __restrict__ aw, const int* __restrict__ scope,
    float* __restrict__ out, unsigned short* __restrict__ lt16) {
  const int tid = threadIdx.x;
  const int wv = tid >> 6;
  const int lane = tid & 63;
  const int b0 = blockIdx.x * GB;

  __shared__ int sscope[GB + 1];
  __shared__ float lg[CHF][3];

  if (tid <= GB) sscope[tid] = scope[b0 + tid];
  __syncthreads();
  const int n0 = sscope[0];
  const int span = sscope[GB] - n0;

  const float4* __restrict__ X4 = (const float4*)x;
  const float4* __restrict__ AW4 = (const float4*)aw;

  // per-wave (bag) running state, replicated across lanes
  float m0 = -INFINITY, m1 = -INFINITY, m2 = -INFINITY;
  float d0 = 0.f, d1 = 0.f, d2 = 0.f;
  float4 acc[3][3];  // [layer][colgroup]
#pragma unroll
  for (int l = 0; l < 3; l++)
#pragma unroll
    for (int k = 0; k < 3; k++) acc[l][k] = make_float4(0.f, 0.f, 0.f, 0.f);

  const int bss = sscope[wv] - n0;      // own bag range within span
  const int bee = sscope[wv + 1] - n0;

  for (int cs = 0; cs < span; cs += CHF) {
    const int clen = min(CHF, span - cs);

    // ---- pass 1: chunk logits, 2 sentences per wave-iteration ----
    for (int i0 = wv; i0 < clen; i0 += 2 * NW) {
      const int i1 = i0 + NW;
      const bool h2 = (i1 < clen);
      const int i1c = h2 ? i1 : i0;
      const int na = n0 + cs + i0;
      const int nb = n0 + cs + i1c;
      const int qa0 = q[3 * na + 0], qa1 = q[3 * na + 1], qa2 = q[3 * na + 2];
      const int qb0 = q[3 * nb + 0], qb1 = q[3 * nb + 1], qb2 = q[3 * nb + 2];
      const float4* xr0 = X4 + (size_t)na * D4;
      const float4* xr1 = X4 + (size_t)nb * D4;
      const float4* A00 = AW4 + (size_t)qa0 * D4;
      const float4* A01 = AW4 + (size_t)qa1 * D4;
      const float4* A02 = AW4 + (size_t)qa2 * D4;
      const float4* A10 = AW4 + (size_t)qb0 * D4;
      const float4* A11 = AW4 + (size_t)qb1 * D4;
      const float4* A12 = AW4 + (size_t)qb2 * D4;
      float p00 = 0.f, p01 = 0.f, p02 = 0.f;
      float p10 = 0.f, p11 = 0.f, p12 = 0.f;
#pragma unroll
      for (int j = 0; j < 3; j++) {
        const int c = lane + 64 * j;
        const float4 x0 = xr0[c];
        const float4 x1 = xr1[c];
        p00 += dot4(x0, A00[c]);
        p01 += dot4(x0, A01[c]);
        p02 += dot4(x0, A02[c]);
        p10 += dot4(x1, A10[c]);
        p11 += dot4(x1, A11[c]);
        p12 += dot4(x1, A12[c]);
      }
      p00 = wsum(p00); p01 = wsum(p01); p02 = wsum(p02);
      p10 = wsum(p10); p11 = wsum(p11); p12 = wsum(p12);
      if (lane == 0) {
        lg[i0][0] = p00; lg[i0][1] = p01; lg[i0][2] = p02;
        if (h2) { lg[i1][0] = p10; lg[i1][1] = p11; lg[i1][2] = p12; }
      }
    }
    __syncthreads();

    // ---- pass 2: wave wv handles its own bag's slice of this chunk ----
    {
      const int ss = max(bss - cs, 0);
      const int ee = min(bee - cs, clen);
      if (ss < ee) {
        // chunk max per layer (lane-parallel over slice)
        float c0 = -INFINITY, c1 = -INFINITY, c2 = -INFINITY;
        for (int i = ss + lane; i < ee; i += 64) {
          c0 = fmaxf(c0, lg[i][0]);
          c1 = fmaxf(c1, lg[i][1]);
          c2 = fmaxf(c2, lg[i][2]);
        }
        c0 = wmax(c0); c1 = wmax(c1); c2 = wmax(c2);
        const float n0m = fmaxf(m0, c0);
        const float n1m = fmaxf(m1, c1);
        const float n2m = fmaxf(m2, c2);
        const float s0 = __expf(m0 - n0m);  // exp(-inf)=0 first time
        const float s1 = __expf(m1 - n1m);
        const float s2 = __expf(m2 - n2m);
        m0 = n0m; m1 = n1m; m2 = n2m;
        d0 *= s0; d1 *= s1; d2 *= s2;
#pragma unroll
        for (int k = 0; k < 3; k++) {
          acc[0][k].x *= s0; acc[0][k].y *= s0; acc[0][k].z *= s0; acc[0][k].w *= s0;
          acc[1][k].x *= s1; acc[1][k].y *= s1; acc[1][k].z *= s1; acc[1][k].w *= s1;
          acc[2][k].x *= s2; acc[2][k].y *= s2; acc[2][k].z *= s2; acc[2][k].w *= s2;
        }
        // weighted accumulate (x rows L1/L2-hot), 2-deep unroll
        int i = ss;
        for (; i + 2 <= ee; i += 2) {
          const int na = n0 + cs + i;
          const int nb = na + 1;
          const float wa0 = __expf(lg[i][0] - m0);
          const float wa1 = __expf(lg[i][1] - m1);
          const float wa2 = __expf(lg[i][2] - m2);
          const float wb0 = __expf(lg[i + 1][0] - m0);
          const float wb1 = __expf(lg[i + 1][1] - m1);
          const float wb2 = __expf(lg[i + 1][2] - m2);
          d0 += wa0 + wb0; d1 += wa1 + wb1; d2 += wa2 + wb2;
#pragma unroll
          for (int k = 0; k < 3; k++) {
            const float4 xa = X4[(size_t)na * D4 + lane + 64 * k];
            const float4 xb = X4[(size_t)nb * D4 + lane + 64 * k];
            acc[0][k].x += wa0 * xa.x + wb0 * xb.x;
            acc[0][k].y += wa0 * xa.y + wb0 * xb.y;
            acc[0][k].z += wa0 * xa.z + wb0 * xb.z;
            acc[0][k].w += wa0 * xa.w + wb0 * xb.w;
            acc[1][k].x += wa1 * xa.x + wb1 * xb.x;
            acc[1][k].y += wa1 * xa.y + wb1 * xb.y;
            acc[1][k].z += wa1 * xa.z + wb1 * xb.z;
            acc[1][k].w += wa1 * xa.w + wb1 * xb.w;
            acc[2][k].x += wa2 * xa.x + wb2 * xb.x;
            acc[2][k].y += wa2 * xa.y + wb2 * xb.y;
            acc[2][k].z += wa2 * xa.z + wb2 * xb.z;
            acc[2][k].w += wa2 * xa.w + wb2 * xb.w;
          }
        }
        if (i < ee) {
          const int na = n0 + cs + i;
          const float wa0 = __expf(lg[i][0] - m0);
          const float wa1 = __expf(lg[i][1] - m1);
          const float wa2 = __expf(lg[i][2] - m2);
          d0 += wa0; d1 += wa1; d2 += wa2;
#pragma unroll
          for (int k = 0; k < 3; k++) {
            const float4 xa = X4[(size_t)na * D4 + lane + 64 * k];
            acc[0][k].x += wa0 * xa.x; acc[0][k].y += wa0 * xa.y;
            acc[0][k].z += wa0 * xa.z; acc[0][k].w += wa0 * xa.w;
            acc[1][k].x += wa1 * xa.x; acc[1][k].y += wa1 * xa.y;
            acc[1][k].z += wa1 * xa.z; acc[1][k].w += wa1 * xa.w;
            acc[2][k].x += wa2 * xa.x; acc[2][k].y += wa2 * xa.y;
            acc[2][k].z += wa2 * xa.z; acc[2][k].w += wa2 * xa.w;
          }
        }
      }
    }
    __syncthreads();  // protect lg before next chunk
  }

  // ---- epilogue: wave wv writes bag b0+wv in all three layouts ----
  const int b = b0 + wv;
  float4* o0 = (float4*)out;                              // stack [3][B][D]
  float4* o1 = (float4*)(out + (size_t)3 * NBAGS * DIM);  // lt [B][3*D]
  ushort4* l16 = (ushort4*)(lt16 + (size_t)b * KTOT);
  const float di[3] = {(d0 > 0.f) ? 1.f / d0 : 0.f,
                       (d1 > 0.f) ? 1.f / d1 : 0.f,
                       (d2 > 0.f) ? 1.f / d2 : 0.f};
#pragma unroll
  for (int l = 0; l < 3; l++) {
#pragma unroll
    for (int k = 0; k < 3; k++) {
      const int c = lane + 64 * k;
      float4 v = acc[l][k];
      v.x *= di[l]; v.y *= di[l]; v.z *= di[l]; v.w *= di[l];
      o0[((size_t)l * NBAGS + b) * D4 + c] = v;
      o1[(size_t)b * K4 + l * D4 + c] = v;
      l16[l * D4 + c] = pk4(v);
    }
  }
}

// ---- K3: probs = lt @ rw^T + bias via bf16 MFMA (64 bags x 64 classes) ----
__global__ __launch_bounds__(256) void probs_mfma(
    const unsigned short* __restrict__ lt16,
    const unsigned short* __restrict__ rw16,
    const float* __restrict__ bias, float* __restrict__ outp) {
  const int wv = threadIdx.x >> 6;
  const int lane = threadIdx.x & 63;
  const int r = lane & 15;
  const int kg = lane >> 4;
  const int bagbase = blockIdx.x * 64 + wv * 16;

  f32x4 acc[4];
#pragma unroll
  for (int ct = 0; ct < 4; ct++) acc[ct] = (f32x4){0.f, 0.f, 0.f, 0.f};

  const unsigned short* ap = lt16 + (size_t)(bagbase + r) * KTOT + kg * 8;
  const unsigned short* bp[4];
#pragma unroll
  for (int ct = 0; ct < 4; ct++)
    bp[ct] = rw16 + (size_t)(ct * 16 + r) * KTOT + kg * 8;

  for (int k = 0; k < KTOT; k += 32) {
    const bf16x8 a = *(const bf16x8*)(ap + k);
#pragma unroll
    for (int ct = 0; ct < 4; ct++) {
      const bf16x8 bb = *(const bf16x8*)(bp[ct] + k);
      acc[ct] = __builtin_amdgcn_mfma_f32_16x16x32_bf16(a, bb, acc[ct], 0, 0, 0);
    }
  }

  // D mapping (m89-verified): col = lane&15, row = (lane>>4)*4 + reg
#pragma unroll
  for (int ct = 0; ct < 4; ct++) {
    const int col = ct * 16 + r;
    if (col < FLATC) {
      const float bv = bias[col];
#pragma unroll
      for (int reg = 0; reg < 4; reg++) {
        const int bag = bagbase + kg * 4 + reg;
        outp[(size_t)bag * FLATC + col] = acc[ct][reg] + bv;
      }
    }
  }
}

extern "C" void kernel_launch(void* const* d_in, const int* in_sizes, int n_in,
                              void* d_out, int out_size, void* d_ws,
                              size_t ws_size, hipStream_t stream) {
  const float* x = (const float*)d_in[0];
  const int* aq = (const int*)d_in[1];
  const int* scope = (const int*)d_in[2];
  const float* aw = (const float*)d_in[3];
  const float* rw = (const float*)d_in[4];
  const float* bias = (const float*)d_in[5];
  float* out = (float*)d_out;

  unsigned short* lt16 = (unsigned short*)d_ws;        // 4096*2304 bf16
  unsigned short* rw16 = lt16 + (size_t)NBAGS * KTOT;  // 64*2304 bf16

  hipLaunchKernelGGL(rwcvt, dim3((CPAD * KTOT + 255) / 256), dim3(256), 0,
                     stream, rw, rw16);
  hipLaunchKernelGGL(fused8, dim3(NBAGS / GB), dim3(512), 0, stream, x, aq,
                     aw, scope, out, lt16);

  float* probs = out + (size_t)3 * NBAGS * DIM + (size_t)NBAGS * KTOT;
  hipLaunchKernelGGL(probs_mfma, dim3(NBAGS / 64), dim3(256), 0, stream, lt16,
                     rw16, bias, probs);
}